// Round 5
// baseline (121.209 us; speedup 1.0000x reference)
//
#include <hip/hip_runtime.h>
#include <hip/hip_bf16.h>
#include <math.h>

// NMI loss, shape (2,1,128,128,128) fp32.
// R1-R4 post-mortems: histogram scatter into LDS is cornered on gfx950 —
// shared hist -> atomic tax (~3.2 cyc/lane, 87us), per-lane private hist ->
// 512B/lane caps occupancy at 1 wave/SIMD -> latency-bound (46us).
// R5: pab = Ia^T * Ib as MFMA outer products (16x16x32 bf16, K=32 voxels).
// Per wave-iteration: 32 voxels; lanes 0-31 own a-side, 32-63 b-side; each
// lane: 1 soft2 -> bf16 pair -> 2 ds_write_b16 into bin-major staging
// [16 bins][32 voxels] (bank = 16*(ka&1)+k/2: conflict-free), after b128
// zeroing. Fragment = ONE ds_read_b128/operand (verified layout
// A[m=lane&15][k=quad*8+j]). DS in-order per wave -> zero barriers.
// Loss is invariant under pab -> pab^T, so transpose errors cancel.

typedef float f32x4  __attribute__((ext_vector_type(4)));
typedef short short8 __attribute__((ext_vector_type(8)));

static constexpr int   V_PER_BATCH = 128 * 128 * 128;   // 2,097,152
static constexpr int   NBINS = 16;
static constexpr int   NB2   = 256;
static constexpr int   BPB   = 256;                     // blocks per batch
static constexpr int   TOTAL_BLOCKS = BPB * 2;          // 512 -> 2 blocks/CU
static constexpr int   ITERS = 64;                      // 32 voxels each
static constexpr float EPSF  = 1e-6f;

// two-bin soft assignment. PRETERM*(spacing)^2 = 50 => third bin <= exp(-50).
__device__ __forceinline__ void soft2(float x, int& k, float& p0, float& p1) {
    float t  = x * 15.0f;
    float kf = floorf(t);
    kf = fminf(fmaxf(kf, 0.0f), 14.0f);
    float f  = t - kf;
    float e  = __builtin_exp2f(144.269504089f * (f - 0.5f));
    p0 = __builtin_amdgcn_rcpf(1.0f + e);
    p1 = 1.0f - p0;
    k  = (int)kf;
}

__global__ __launch_bounds__(256) void nmi_mfma(
        const float* __restrict__ ytrue,
        const float* __restrict__ ypred,
        float* __restrict__ ghist,           // [2][256] f32, zeroed
        unsigned int* __restrict__ counter,  // [1], zeroed
        float* __restrict__ out)             // [2]
{
    // per-wave staging: A rows [0..511] shorts, B rows [512..1023]
    __shared__ __align__(16) short stage[4][1024];   // 8 KB
    __shared__ float cred[4][NB2];                   // 4 KB epilogue

    const int tid  = threadIdx.x;
    const int wave = tid >> 6;
    const int lane = tid & 63;
    const int k    = lane & 31;          // voxel index within chunk
    const int m    = lane & 15;          // bin (fragment row)
    const int quad = lane >> 4;
    const bool isB = lane >= 32;
    const int batch = blockIdx.y;

    short* st = stage[wave];
    uint4* stz = reinterpret_cast<uint4*>(st);                 // 128 uint4
    const short8* aFrag = reinterpret_cast<const short8*>(st + m * 32 + quad * 8);
    const short8* bFrag = reinterpret_cast<const short8*>(st + 512 + m * 32 + quad * 8);
    short* scat = st + (isB ? 512 : 0);

    // this wave's voxel span: gw in [0,1024) per batch, 2048 voxels each
    const int gw = (blockIdx.x << 2) | wave;
    const float* src = (isB ? ypred : ytrue)
                     + (size_t)batch * V_PER_BATCH + (size_t)gw * 2048 + k;

    f32x4 acc = {0.f, 0.f, 0.f, 0.f};
    float cur = src[0];

    #pragma unroll 4
    for (int it = 0; it < ITERS; ++it) {
        float nxt = src[((it + 1) & 63) * 32];   // wraps in-bounds on last iter

        int kq; float p0, p1;
        soft2(cur, kq, p0, p1);
        __hip_bfloat162 h2 = __float22bfloat162_rn(make_float2(p0, p1));
        unsigned pk = *reinterpret_cast<unsigned*>(&h2);   // low16=p0, high16=p1

        // zero this wave's 2KB staging (in-order DS: after last iter's reads)
        const uint4 z = make_uint4(0u, 0u, 0u, 0u);
        stz[lane]      = z;
        stz[lane + 64] = z;

        // scatter: rows kq and kq+1, column k (conflict-free banking)
        short* dst = scat + kq * 32 + k;
        dst[0]  = (short)(pk & 0xFFFFu);
        dst[32] = (short)(pk >> 16);

        // fragments + MFMA (compiler inserts lgkmcnt; DS FIFO gives RAW)
        short8 a8 = *aFrag;
        short8 b8 = *bFrag;
        acc = __builtin_amdgcn_mfma_f32_16x16x32_bf16(a8, b8, acc, 0, 0, 0);

        cur = nxt;
    }

    // --- block epilogue: reduce 4 waves' C tiles, one global atomic per cell
    #pragma unroll
    for (int r = 0; r < 4; ++r)
        cred[wave][(quad * 4 + r) * 16 + m] = acc[r];
    __syncthreads();

    float v = cred[0][tid] + cred[1][tid] + cred[2][tid] + cred[3][tid];
    atomicAdd(&ghist[batch * NB2 + tid], v);

    // --- last-block-done: final arriver computes entropies
    __threadfence();
    __syncthreads();
    __shared__ int is_last;
    if (tid == 0) {
        unsigned prev = atomicAdd(counter, 1u);
        is_last = (prev == (unsigned)(TOTAL_BLOCKS - 1));
    }
    __syncthreads();
    if (!is_last) return;
    __threadfence();

    __shared__ float pab[NB2];
    __shared__ float red[NB2];
    __shared__ float hx[NBINS], hy[NBINS];
    const float toP = 1.0f / (float)V_PER_BATCH;

    for (int b = 0; b < 2; ++b) {
        float p = __hip_atomic_load(&ghist[b * NB2 + tid],
                                    __ATOMIC_RELAXED, __HIP_MEMORY_SCOPE_AGENT) * toP;
        pab[tid] = p;
        red[tid] = p * log2f(p + EPSF);
        __syncthreads();

        for (int s = NB2 / 2; s > 0; s >>= 1) {
            if (tid < s) red[tid] += red[tid + s];
            __syncthreads();
        }

        if (tid < NBINS) {
            float pa = 0.0f, pb = 0.0f;
            #pragma unroll
            for (int j = 0; j < NBINS; ++j) {
                pa += pab[tid * NBINS + j];
                pb += pab[j * NBINS + tid];
            }
            hx[tid] = pa * log2f(pa + EPSF);
            hy[tid] = pb * log2f(pb + EPSF);
        }
        __syncthreads();

        if (tid == 0) {
            float Hxy = -red[0];
            float Hx = 0.0f, Hy = 0.0f;
            #pragma unroll
            for (int i = 0; i < NBINS; ++i) { Hx += hx[i]; Hy += hy[i]; }
            Hx = -Hx; Hy = -Hy;
            float nmi = 2.0f * (1.0f - Hxy / (Hx + Hy));
            out[b] = 1.0f - nmi;
        }
        __syncthreads();
    }
}

extern "C" void kernel_launch(void* const* d_in, const int* in_sizes, int n_in,
                              void* d_out, int out_size, void* d_ws, size_t ws_size,
                              hipStream_t stream) {
    const float* ytrue = (const float*)d_in[0];
    const float* ypred = (const float*)d_in[1];
    float* out = (float*)d_out;

    float* ghist          = (float*)d_ws;                         // 512 * 4B = 2 KB
    unsigned int* counter = (unsigned int*)((char*)d_ws + 4096);  // 4 B

    hipMemsetAsync(d_ws, 0, 4096 + 64, stream);

    dim3 grid(BPB, 2);
    nmi_mfma<<<grid, 256, 0, stream>>>(ytrue, ypred, ghist, counter, out);
}